// Round 23
// baseline (348.485 us; speedup 1.0000x reference)
//
#include <hip/hip_runtime.h>

#define S 3072
#define D 512
#define H 8

constexpr float LN_EPS = 1e-6f;

typedef __attribute__((ext_vector_type(2))) _Float16 f16x2;
typedef __attribute__((ext_vector_type(8))) _Float16 f16x8;  // 8 f16 = 4 VGPRs
typedef __attribute__((ext_vector_type(4))) float f32x4;     // MFMA C/D frag

__device__ __forceinline__ f16x2 cvt_pk(float lo, float hi) {
    return __builtin_bit_cast(f16x2, __builtin_amdgcn_cvt_pkrtz(lo, hi));
}

// -------------------- P0a: W transpose + fp16 convert --------------------
__global__ void prep_w_kernel(const float* __restrict__ Wq, const float* __restrict__ Wk,
                              const float* __restrict__ Wv, const float* __restrict__ Wo,
                              _Float16* __restrict__ WtAll) {
    const int c  = blockIdx.x * 256 + threadIdx.x;   // 0..511
    const int k0 = blockIdx.y * 64;
    const int mat = blockIdx.z;
    const float* W = (mat == 0) ? Wq : (mat == 1) ? Wk : (mat == 2) ? Wv : Wo;
    _Float16* dst = WtAll + ((size_t)(mat * 512 + c)) * 512 + k0;
#pragma unroll
    for (int kb = 0; kb < 8; ++kb) {
        f16x8 v;
#pragma unroll
        for (int i = 0; i < 8; ++i)
            v[i] = (_Float16)W[(size_t)(k0 + kb * 8 + i) * 512 + c];
        *(f16x8*)(dst + kb * 8) = v;
    }
}

// -------------------- P0b: x -> fp16 --------------------
__global__ void prep_x_kernel(const float* __restrict__ x, _Float16* __restrict__ xh) {
    const int i = blockIdx.x * 256 + threadIdx.x;
    const float4* xf = (const float4*)x;
    float4 a = xf[i * 2], b = xf[i * 2 + 1];
    f16x8 v = {(_Float16)a.x, (_Float16)a.y, (_Float16)a.z, (_Float16)a.w,
               (_Float16)b.x, (_Float16)b.y, (_Float16)b.z, (_Float16)b.w};
    *(f16x8*)(xh + (size_t)i * 8) = v;
}

// -------------------- K1: QKV projection (MFMA) --------------------
__global__ __launch_bounds__(256) void qkv_mfma_kernel(
        const _Float16* __restrict__ xh, const _Float16* __restrict__ WtAll,
        const float* __restrict__ bq, const float* __restrict__ bk,
        const float* __restrict__ bv,
        _Float16* __restrict__ Qb, _Float16* __restrict__ Kb,
        _Float16* __restrict__ Vt) {
    const int t = threadIdx.x;
    const int w = t >> 6, l = t & 63, lr = l & 15, lk = l >> 4;
    const int r0 = blockIdx.x * 64 + w * 16;
    const int c0 = blockIdx.y * 64;
    const _Float16* Ar = xh + (size_t)(r0 + lr) * 512 + lk * 8;
    const _Float16* Br = WtAll + (size_t)(c0 + lr) * 512 + lk * 8;

    f32x4 acc[4];
#pragma unroll
    for (int j = 0; j < 4; ++j) acc[j] = (f32x4){0.f, 0.f, 0.f, 0.f};
    for (int ks = 0; ks < 16; ++ks) {
        f16x8 a = *(const f16x8*)(Ar + ks * 32);
#pragma unroll
        for (int j = 0; j < 4; ++j) {
            f16x8 b = *(const f16x8*)(Br + (size_t)(j * 16) * 512 + ks * 32);
            acc[j] = __builtin_amdgcn_mfma_f32_16x16x32_f16(a, b, acc[j], 0, 0, 0);
        }
    }
    const int m = c0 >> 9;                   // block-uniform: 0=Q 1=K 2=V
    const float* bias = (m == 0) ? bq : (m == 1) ? bk : bv;
#pragma unroll
    for (int j = 0; j < 4; ++j) {
        const int cc = (c0 & 511) + j * 16 + lr;
        const int h = cc >> 6, d = cc & 63;
        const float bb_ = bias[cc];
#pragma unroll
        for (int r = 0; r < 4; ++r) {
            const int row = r0 + lk * 4 + r;
            float val = acc[j][r] + bb_;
            if (m == 0)      Qb[((size_t)h * S + row) * 64 + d] = (_Float16)(val * 0.0625f);
            else if (m == 1) Kb[((size_t)h * S + row) * 64 + d] = (_Float16)val;
            else {
                int bb = row & 31;
                int sp = (row & ~31) | (((bb & 15) << 1) | (bb >> 4));
                Vt[((size_t)h * 64 + d) * S + sp] = (_Float16)val;
            }
        }
    }
}

// -------------------- K2: fused logits + entmax-1.5 + PV --------------------
// Newton-slim base (r20/22) with Phase T and PV MERGED per-jp: each jp's two
// nontemporal f32x4 attn stores interleave with its 4 PV MFMAs, so the
// write-bound phase (302 MB @ ~5 TB/s) overlaps the MFMA phase instead of
// serializing. zw is scratch-resident either way (VGPR_Count=52 proves the
// compiler never kept it in regs); hot set in the merged loop is acc(16) +
// temps, which fits under (512,3)'s ~85 cap.
__global__ __launch_bounds__(512, 3) void fused_attn_kernel(
        const _Float16* __restrict__ Qb, const _Float16* __restrict__ Kb,
        const _Float16* __restrict__ Vt, float* __restrict__ attn,
        _Float16* __restrict__ AOh) {
    __shared__ float sred[2][8][16][2];                 // ping-pong stats (2 KB)
    __shared__ float smax[8][16];                       // Pass A max (0.5 KB)
    __shared__ __align__(16) f16x2 plds[2][8][16][20];  // padded transpose (20.5 KB)
    __shared__ float pacc[16][64];                      // PV reduction (4 KB)
    const int bid = blockIdx.x;
    const int h = bid & 7, qt = bid >> 3;    // one head per XCD
    const int q0 = qt * 16;
    const int t = threadIdx.x;
    const int w = t >> 6, l = t & 63;
    const int lr = l & 15, lk = l >> 4;
    const int kbase = w * 384;

    ((float*)pacc)[t] = 0.f;
    ((float*)pacc)[t + 512] = 0.f;

    const _Float16* Qh = Qb + ((size_t)h * S) * 64;
    const _Float16* Kh = Kb + ((size_t)h * S) * 64;
    const _Float16* Vh = Vt + (size_t)h * 64 * S;

    const f16x8 aq0 = *(const f16x8*)(Qh + (size_t)(q0 + lr) * 64 + lk * 8);
    const f16x8 aq1 = *(const f16x8*)(Qh + (size_t)(q0 + lr) * 64 + 32 + lk * 8);

    const f16x2 one2  = {(_Float16)1.f, (_Float16)1.f};
    const f16x2 zero2 = {(_Float16)0.f, (_Float16)0.f};

    // ---- Pass A: logits once (already w-space); packed stats ----
    f16x2 zw[12][4];
    f16x2 m2[4];
    float s4[4] = {}, q4[4] = {};
#pragma unroll
    for (int r = 0; r < 4; ++r) m2[r] = (f16x2){(_Float16)-60000.f, (_Float16)-60000.f};
#pragma unroll
    for (int jp = 0; jp < 12; ++jp) {
        const _Float16* kp = Kh + (size_t)(kbase + jp * 32 + lr) * 64;
        f16x8 b00 = *(const f16x8*)(kp + lk * 8);
        f16x8 b01 = *(const f16x8*)(kp + 32 + lk * 8);
        f16x8 b10 = *(const f16x8*)(kp + 16 * 64 + lk * 8);
        f16x8 b11 = *(const f16x8*)(kp + 16 * 64 + 32 + lk * 8);
        f32x4 d0 = (f32x4){0.f, 0.f, 0.f, 0.f}, d1 = d0;
        d0 = __builtin_amdgcn_mfma_f32_16x16x32_f16(aq0, b00, d0, 0, 0, 0);
        d0 = __builtin_amdgcn_mfma_f32_16x16x32_f16(aq1, b01, d0, 0, 0, 0);
        d1 = __builtin_amdgcn_mfma_f32_16x16x32_f16(aq0, b10, d1, 0, 0, 0);
        d1 = __builtin_amdgcn_mfma_f32_16x16x32_f16(aq1, b11, d1, 0, 0, 0);
#pragma unroll
        for (int r = 0; r < 4; ++r) {
            f16x2 w2 = cvt_pk(d0[r], d1[r]);
            zw[jp][r] = w2;
            m2[r] = __builtin_elementwise_max(m2[r], w2);
            s4[r] = __builtin_amdgcn_fdot2(w2, one2, s4[r], false);
            q4[r] = __builtin_amdgcn_fdot2(w2, w2, q4[r], false);
        }
    }
    float m4[4];
#pragma unroll
    for (int r = 0; r < 4; ++r) m4[r] = fmaxf((float)m2[r][0], (float)m2[r][1]);
#pragma unroll
    for (int off = 1; off < 16; off <<= 1) {
#pragma unroll
        for (int r = 0; r < 4; ++r) {
            m4[r] = fmaxf(m4[r], __shfl_xor(m4[r], off, 64));
            s4[r] += __shfl_xor(s4[r], off, 64);
            q4[r] += __shfl_xor(q4[r], off, 64);
        }
    }
    if (lr == 0) {
#pragma unroll
        for (int r = 0; r < 4; ++r) {
            smax[w][lk * 4 + r]        = m4[r];
            sred[0][w][lk * 4 + r][0]  = s4[r];
            sred[0][w][lk * 4 + r][1]  = q4[r];
        }
    }
    __syncthreads();

    // ---- closed-form full-support init (w-space) ----
    const float n = (float)S;
    float Tj;
    {
        float mj = -1e30f, sj = 0.f, qj = 0.f;
#pragma unroll
        for (int ww = 0; ww < 8; ++ww) {
            mj = fmaxf(mj, smax[ww][lr]);
            sj += sred[0][ww][lr][0];
            qj += sred[0][ww][lr][1];
        }
        float mean = sj * (1.f / n);
        float msq  = qj * (1.f / n);
        float ssv  = n * (msq - mean * mean);
        Tj = mean - sqrtf(fmaxf((1.f - ssv) / n, 0.f));
        Tj = fminf(fmaxf(Tj, mj - 1.0f), mj - 0.01f);
    }
    float T4[4];
#pragma unroll
    for (int r = 0; r < 4; ++r) T4[r] = __shfl(Tj, lk * 4 + r, 64);

    // ---- Pass B: register-only packed NEWTON iterations ----
    for (int it = 0; it < 6; ++it) {
        const int buf = (it + 1) & 1;
        f16x2 T2[4];
#pragma unroll
        for (int r = 0; r < 4; ++r) T2[r] = cvt_pk(T4[r], T4[r]);
        float f4[4] = {}, fp4[4] = {};
#pragma unroll
        for (int jp = 0; jp < 12; ++jp)
#pragma unroll
            for (int r = 0; r < 4; ++r) {
                f16x2 zc = __builtin_elementwise_max(zw[jp][r] - T2[r], zero2);
                f4[r]  = __builtin_amdgcn_fdot2(zc, zc, f4[r], false);
                fp4[r] = __builtin_amdgcn_fdot2(zc, one2, fp4[r], false);
            }
#pragma unroll
        for (int off = 1; off < 16; off <<= 1) {
#pragma unroll
            for (int r = 0; r < 4; ++r) {
                f4[r]  += __shfl_xor(f4[r],  off, 64);
                fp4[r] += __shfl_xor(fp4[r], off, 64);
            }
        }
        if (lr == 0) {
#pragma unroll
            for (int r = 0; r < 4; ++r) {
                sred[buf][w][lk * 4 + r][0] = f4[r];
                sred[buf][w][lk * 4 + r][1] = fp4[r];
            }
        }
        __syncthreads();
        float fj = 0.f, fpj = 0.f;
#pragma unroll
        for (int ww = 0; ww < 8; ++ww) {
            fj  += sred[buf][ww][lr][0];
            fpj += sred[buf][ww][lr][1];
        }
        float del = (fj - 1.0f) / (2.0f * fpj + 1e-20f);   // Newton step
        Tj += del;
#pragma unroll
        for (int r = 0; r < 4; ++r) T4[r] = __shfl(Tj, lk * 4 + r, 64);
        if (__all(fabsf(del) < 1e-6f)) break;   // block-uniform
    }

    // ---- Merged Phase T+PV per jp: stores interleave with PV MFMAs ----
    f16x2 T2[4];
#pragma unroll
    for (int r = 0; r < 4; ++r) T2[r] = cvt_pk(T4[r], T4[r]);
    float* arow_t = attn + ((size_t)h * S + q0 + lr) * S + kbase + lk * 4;
    const _Float16* vp0 = Vh + (size_t)(0 * 16 + lr) * S + kbase + lk * 8;
    const _Float16* vp1 = Vh + (size_t)(1 * 16 + lr) * S + kbase + lk * 8;
    const _Float16* vp2 = Vh + (size_t)(2 * 16 + lr) * S + kbase + lk * 8;
    const _Float16* vp3 = Vh + (size_t)(3 * 16 + lr) * S + kbase + lk * 8;
    f32x4 acc[4];
#pragma unroll
    for (int j = 0; j < 4; ++j) acc[j] = (f32x4){0.f, 0.f, 0.f, 0.f};
#pragma unroll
    for (int jp = 0; jp < 12; ++jp) {
        const int buf = jp & 1;
        union { f16x2 h2[4]; f16x8 v; } pw;
#pragma unroll
        for (int r = 0; r < 4; ++r) {
            f16x2 zc = __builtin_elementwise_max(zw[jp][r] - T2[r], zero2);
            pw.h2[r] = zc * zc;
        }
        *(f16x8*)&plds[buf][w][lr][lk * 4] = pw.v;
        union { f16x2 h2[4]; f16x8 v; } au;
#pragma unroll
        for (int u = 0; u < 4; ++u) au.h2[u] = plds[buf][w][lk * 4 + u][lr];
        f32x4 lo = {(float)au.v[0], (float)au.v[2], (float)au.v[4], (float)au.v[6]};
        f32x4 hi = {(float)au.v[1], (float)au.v[3], (float)au.v[5], (float)au.v[7]};
        __builtin_nontemporal_store(lo, (f32x4*)(arow_t + jp * 32));
        __builtin_nontemporal_store(hi, (f32x4*)(arow_t + jp * 32 + 16));
        acc[0] = __builtin_amdgcn_mfma_f32_16x16x32_f16(au.v, *(const f16x8*)(vp0 + jp * 32), acc[0], 0, 0, 0);
        acc[1] = __builtin_amdgcn_mfma_f32_16x16x32_f16(au.v, *(const f16x8*)(vp1 + jp * 32), acc[1], 0, 0, 0);
        acc[2] = __builtin_amdgcn_mfma_f32_16x16x32_f16(au.v, *(const f16x8*)(vp2 + jp * 32), acc[2], 0, 0, 0);
        acc[3] = __builtin_amdgcn_mfma_f32_16x16x32_f16(au.v, *(const f16x8*)(vp3 + jp * 32), acc[3], 0, 0, 0);
    }
#pragma unroll
    for (int j = 0; j < 4; ++j)
#pragma unroll
        for (int r = 0; r < 4; ++r)
            atomicAdd(&pacc[lk * 4 + r][j * 16 + lr], acc[j][r]);
    __syncthreads();
    _Float16* AOr = AOh + (size_t)q0 * 512 + h * 64;
#pragma unroll
    for (int u = 0; u < 2; ++u) {
        int idx = t + 512 * u;             // 0..1023
        int row = idx >> 6, col = idx & 63;
        AOr[(size_t)row * 512 + col] = (_Float16)pacc[row][col];
    }
}

// -------------------- K5: out-proj + residual + LayerNorm (MFMA, 8 waves) --------------------
__global__ __launch_bounds__(512) void outproj_mfma_kernel(
        const _Float16* __restrict__ AOh, const _Float16* __restrict__ WtAll,
        const float* __restrict__ bo, const float* __restrict__ x,
        const float* __restrict__ gamma, const float* __restrict__ beta,
        float* __restrict__ out) {
    __shared__ float red[8][16][2];
    const int s0 = blockIdx.x * 16;
    const int t = threadIdx.x, w = t >> 6, l = t & 63;
    const int lr = l & 15, lk = l >> 4;
    const _Float16* Ar = AOh + (size_t)(s0 + lr) * 512 + lk * 8;
    const _Float16* Br = WtAll + (size_t)(1536 + w * 64 + lr) * 512 + lk * 8;

    f32x4 acc[4];
#pragma unroll
    for (int j = 0; j < 4; ++j) acc[j] = (f32x4){0.f, 0.f, 0.f, 0.f};
    for (int ks = 0; ks < 16; ++ks) {
        f16x8 a = *(const f16x8*)(Ar + ks * 32);
#pragma unroll
        for (int j = 0; j < 4; ++j) {
            f16x8 b = *(const f16x8*)(Br + (size_t)(j * 16) * 512 + ks * 32);
            acc[j] = __builtin_amdgcn_mfma_f32_16x16x32_f16(a, b, acc[j], 0, 0, 0);
        }
    }
    float s_[4] = {}, q_[4] = {};
#pragma unroll
    for (int j = 0; j < 4; ++j) {
        const int col = w * 64 + j * 16 + lr;
        const float b0 = bo[col];
#pragma unroll
        for (int r = 0; r < 4; ++r) {
            float y = acc[j][r] + b0 + x[(size_t)(s0 + lk * 4 + r) * 512 + col];
            acc[j][r] = y;
            s_[r] += y;
            q_[r] = fmaf(y, y, q_[r]);
        }
    }
#pragma unroll
    for (int off = 1; off < 16; off <<= 1) {
#pragma unroll
        for (int r = 0; r < 4; ++r) {
            s_[r] += __shfl_xor(s_[r], off, 64);
            q_[r] += __shfl_xor(q_[r], off, 64);
        }
    }
    if (lr == 0) {
#pragma unroll
        for (int r = 0; r < 4; ++r) {
            red[w][lk * 4 + r][0] = s_[r];
            red[w][lk * 4 + r][1] = q_[r];
        }
    }
    __syncthreads();
#pragma unroll
    for (int r = 0; r < 4; ++r) {
        const int rowi = lk * 4 + r;
        float sj = 0.f, qj = 0.f;
#pragma unroll
        for (int ww = 0; ww < 8; ++ww) { sj += red[ww][rowi][0]; qj += red[ww][rowi][1]; }
        float mu  = sj * (1.0f / 512.0f);
        float var = qj * (1.0f / 512.0f) - mu * mu;
        float inv = rsqrtf(var + LN_EPS);
        const size_t rbase = (size_t)(s0 + rowi) * 512;
#pragma unroll
        for (int j = 0; j < 4; ++j) {
            const int col = w * 64 + j * 16 + lr;
            out[rbase + col] = (acc[j][r] - mu) * inv * gamma[col] + beta[col];
        }
    }
}

extern "C" void kernel_launch(void* const* d_in, const int* in_sizes, int n_in,
                              void* d_out, int out_size, void* d_ws, size_t ws_size,
                              hipStream_t stream) {
    const float* x     = (const float*)d_in[0];
    const float* Wq    = (const float*)d_in[1];
    const float* bq    = (const float*)d_in[2];
    const float* Wk    = (const float*)d_in[3];
    const float* bk    = (const float*)d_in[4];
    const float* Wv    = (const float*)d_in[5];
    const float* bv    = (const float*)d_in[6];
    const float* Wo    = (const float*)d_in[7];
    const float* bo    = (const float*)d_in[8];
    const float* gamma = (const float*)d_in[9];
    const float* beta  = (const float*)d_in[10];

    float* out  = (float*)d_out;
    float* attn = out + (size_t)S * D;          // tuple output #2

    _Float16* Qb    = (_Float16*)d_ws;          // [H][S][64] fp16, pre-scaled 1/16
    _Float16* Kb    = Qb + (size_t)H * S * 64;  // [H][S][64] fp16
    _Float16* Vt    = Kb + (size_t)H * S * 64;  // [H][64][S] fp16, k-interleaved
    _Float16* xh    = Vt + (size_t)H * S * 64;  // [S][512] fp16
    _Float16* WtAll = xh + (size_t)S * 512;     // [2048][512] fp16
    _Float16* AOh   = WtAll + (size_t)2048 * 512; // [S][512] fp16

    prep_w_kernel<<<dim3(2, 8, 4), 256, 0, stream>>>(Wq, Wk, Wv, Wo, WtAll);
    prep_x_kernel<<<dim3(S * D / 2048), 256, 0, stream>>>(x, xh);
    qkv_mfma_kernel<<<dim3(48, 24), 256, 0, stream>>>(xh, WtAll, bq, bk, bv, Qb, Kb, Vt);
    fused_attn_kernel<<<dim3((S / 16) * H), 512, 0, stream>>>(Qb, Kb, Vt, attn, AOh);
    outproj_mfma_kernel<<<dim3(S / 16), 512, 0, stream>>>(AOh, WtAll, bo, x, gamma, beta, out);
}

// Round 24
// 270.489 us; speedup vs baseline: 1.2884x; 1.2884x over previous
//
#include <hip/hip_runtime.h>

#define S 3072
#define D 512
#define H 8

constexpr float LN_EPS = 1e-6f;

typedef __attribute__((ext_vector_type(2))) _Float16 f16x2;
typedef __attribute__((ext_vector_type(8))) _Float16 f16x8;  // 8 f16 = 4 VGPRs
typedef __attribute__((ext_vector_type(4))) float f32x4;     // MFMA C/D frag

__device__ __forceinline__ f16x2 cvt_pk(float lo, float hi) {
    return __builtin_bit_cast(f16x2, __builtin_amdgcn_cvt_pkrtz(lo, hi));
}

// -------------------- P0a: W transpose + fp16 convert --------------------
__global__ void prep_w_kernel(const float* __restrict__ Wq, const float* __restrict__ Wk,
                              const float* __restrict__ Wv, const float* __restrict__ Wo,
                              _Float16* __restrict__ WtAll) {
    const int c  = blockIdx.x * 256 + threadIdx.x;   // 0..511
    const int k0 = blockIdx.y * 64;
    const int mat = blockIdx.z;
    const float* W = (mat == 0) ? Wq : (mat == 1) ? Wk : (mat == 2) ? Wv : Wo;
    _Float16* dst = WtAll + ((size_t)(mat * 512 + c)) * 512 + k0;
#pragma unroll
    for (int kb = 0; kb < 8; ++kb) {
        f16x8 v;
#pragma unroll
        for (int i = 0; i < 8; ++i)
            v[i] = (_Float16)W[(size_t)(k0 + kb * 8 + i) * 512 + c];
        *(f16x8*)(dst + kb * 8) = v;
    }
}

// -------------------- P0b: x -> fp16 --------------------
__global__ void prep_x_kernel(const float* __restrict__ x, _Float16* __restrict__ xh) {
    const int i = blockIdx.x * 256 + threadIdx.x;
    const float4* xf = (const float4*)x;
    float4 a = xf[i * 2], b = xf[i * 2 + 1];
    f16x8 v = {(_Float16)a.x, (_Float16)a.y, (_Float16)a.z, (_Float16)a.w,
               (_Float16)b.x, (_Float16)b.y, (_Float16)b.z, (_Float16)b.w};
    *(f16x8*)(xh + (size_t)i * 8) = v;
}

// -------------------- K1: QKV projection (MFMA) --------------------
__global__ __launch_bounds__(256) void qkv_mfma_kernel(
        const _Float16* __restrict__ xh, const _Float16* __restrict__ WtAll,
        const float* __restrict__ bq, const float* __restrict__ bk,
        const float* __restrict__ bv,
        _Float16* __restrict__ Qb, _Float16* __restrict__ Kb,
        _Float16* __restrict__ Vt) {
    const int t = threadIdx.x;
    const int w = t >> 6, l = t & 63, lr = l & 15, lk = l >> 4;
    const int r0 = blockIdx.x * 64 + w * 16;
    const int c0 = blockIdx.y * 64;
    const _Float16* Ar = xh + (size_t)(r0 + lr) * 512 + lk * 8;
    const _Float16* Br = WtAll + (size_t)(c0 + lr) * 512 + lk * 8;

    f32x4 acc[4];
#pragma unroll
    for (int j = 0; j < 4; ++j) acc[j] = (f32x4){0.f, 0.f, 0.f, 0.f};
    for (int ks = 0; ks < 16; ++ks) {
        f16x8 a = *(const f16x8*)(Ar + ks * 32);
#pragma unroll
        for (int j = 0; j < 4; ++j) {
            f16x8 b = *(const f16x8*)(Br + (size_t)(j * 16) * 512 + ks * 32);
            acc[j] = __builtin_amdgcn_mfma_f32_16x16x32_f16(a, b, acc[j], 0, 0, 0);
        }
    }
    const int m = c0 >> 9;                   // block-uniform: 0=Q 1=K 2=V
    const float* bias = (m == 0) ? bq : (m == 1) ? bk : bv;
#pragma unroll
    for (int j = 0; j < 4; ++j) {
        const int cc = (c0 & 511) + j * 16 + lr;
        const int h = cc >> 6, d = cc & 63;
        const float bb_ = bias[cc];
#pragma unroll
        for (int r = 0; r < 4; ++r) {
            const int row = r0 + lk * 4 + r;
            float val = acc[j][r] + bb_;
            if (m == 0)      Qb[((size_t)h * S + row) * 64 + d] = (_Float16)(val * 0.0625f);
            else if (m == 1) Kb[((size_t)h * S + row) * 64 + d] = (_Float16)val;
            else {
                int bb = row & 31;
                int sp = (row & ~31) | (((bb & 15) << 1) | (bb >> 4));
                Vt[((size_t)h * 64 + d) * S + sp] = (_Float16)val;
            }
        }
    }
}

// -------------------- K2: fused logits + entmax-1.5 + PV --------------------
// r20 configuration verbatim -- best measured of 23 rounds (199 us fused /
// 270.7 us total): Newton Pass B, SEPARATE Phase T / Phase PV (merging pushes
// VGPR past the 64-reg occupancy step: 42%->23%, r18/r23), azw[12] epilogue
// array (spills ~90 MB but beats all alternatives), launch_bounds(512,4).
__global__ __launch_bounds__(512, 4) void fused_attn_kernel(
        const _Float16* __restrict__ Qb, const _Float16* __restrict__ Kb,
        const _Float16* __restrict__ Vt, float* __restrict__ attn,
        _Float16* __restrict__ AOh) {
    __shared__ float sred[2][8][16][2];                 // ping-pong stats (2 KB)
    __shared__ float smax[8][16];                       // Pass A max (0.5 KB)
    __shared__ __align__(16) f16x2 plds[2][8][16][20];  // padded transpose (20.5 KB)
    __shared__ float pacc[16][64];                      // PV reduction (4 KB)
    const int bid = blockIdx.x;
    const int h = bid & 7, qt = bid >> 3;    // one head per XCD
    const int q0 = qt * 16;
    const int t = threadIdx.x;
    const int w = t >> 6, l = t & 63;
    const int lr = l & 15, lk = l >> 4;
    const int kbase = w * 384;

    ((float*)pacc)[t] = 0.f;
    ((float*)pacc)[t + 512] = 0.f;

    const _Float16* Qh = Qb + ((size_t)h * S) * 64;
    const _Float16* Kh = Kb + ((size_t)h * S) * 64;
    const _Float16* Vh = Vt + (size_t)h * 64 * S;

    const f16x8 aq0 = *(const f16x8*)(Qh + (size_t)(q0 + lr) * 64 + lk * 8);
    const f16x8 aq1 = *(const f16x8*)(Qh + (size_t)(q0 + lr) * 64 + 32 + lk * 8);

    const f16x2 one2  = {(_Float16)1.f, (_Float16)1.f};
    const f16x2 zero2 = {(_Float16)0.f, (_Float16)0.f};

    // ---- Pass A: logits once (already w-space); packed stats ----
    f16x2 zw[12][4];
    f16x2 m2[4];
    float s4[4] = {}, q4[4] = {};
#pragma unroll
    for (int r = 0; r < 4; ++r) m2[r] = (f16x2){(_Float16)-60000.f, (_Float16)-60000.f};
#pragma unroll
    for (int jp = 0; jp < 12; ++jp) {
        const _Float16* kp = Kh + (size_t)(kbase + jp * 32 + lr) * 64;
        f16x8 b00 = *(const f16x8*)(kp + lk * 8);
        f16x8 b01 = *(const f16x8*)(kp + 32 + lk * 8);
        f16x8 b10 = *(const f16x8*)(kp + 16 * 64 + lk * 8);
        f16x8 b11 = *(const f16x8*)(kp + 16 * 64 + 32 + lk * 8);
        f32x4 d0 = (f32x4){0.f, 0.f, 0.f, 0.f}, d1 = d0;
        d0 = __builtin_amdgcn_mfma_f32_16x16x32_f16(aq0, b00, d0, 0, 0, 0);
        d0 = __builtin_amdgcn_mfma_f32_16x16x32_f16(aq1, b01, d0, 0, 0, 0);
        d1 = __builtin_amdgcn_mfma_f32_16x16x32_f16(aq0, b10, d1, 0, 0, 0);
        d1 = __builtin_amdgcn_mfma_f32_16x16x32_f16(aq1, b11, d1, 0, 0, 0);
#pragma unroll
        for (int r = 0; r < 4; ++r) {
            f16x2 w2 = cvt_pk(d0[r], d1[r]);
            zw[jp][r] = w2;
            m2[r] = __builtin_elementwise_max(m2[r], w2);
            s4[r] = __builtin_amdgcn_fdot2(w2, one2, s4[r], false);
            q4[r] = __builtin_amdgcn_fdot2(w2, w2, q4[r], false);
        }
    }
    float m4[4];
#pragma unroll
    for (int r = 0; r < 4; ++r) m4[r] = fmaxf((float)m2[r][0], (float)m2[r][1]);
#pragma unroll
    for (int off = 1; off < 16; off <<= 1) {
#pragma unroll
        for (int r = 0; r < 4; ++r) {
            m4[r] = fmaxf(m4[r], __shfl_xor(m4[r], off, 64));
            s4[r] += __shfl_xor(s4[r], off, 64);
            q4[r] += __shfl_xor(q4[r], off, 64);
        }
    }
    if (lr == 0) {
#pragma unroll
        for (int r = 0; r < 4; ++r) {
            smax[w][lk * 4 + r]        = m4[r];
            sred[0][w][lk * 4 + r][0]  = s4[r];
            sred[0][w][lk * 4 + r][1]  = q4[r];
        }
    }
    __syncthreads();

    // ---- closed-form full-support init (w-space) ----
    const float n = (float)S;
    float Tj;
    {
        float mj = -1e30f, sj = 0.f, qj = 0.f;
#pragma unroll
        for (int ww = 0; ww < 8; ++ww) {
            mj = fmaxf(mj, smax[ww][lr]);
            sj += sred[0][ww][lr][0];
            qj += sred[0][ww][lr][1];
        }
        float mean = sj * (1.f / n);
        float msq  = qj * (1.f / n);
        float ssv  = n * (msq - mean * mean);
        Tj = mean - sqrtf(fmaxf((1.f - ssv) / n, 0.f));
        Tj = fminf(fmaxf(Tj, mj - 1.0f), mj - 0.01f);
    }
    float T4[4];
#pragma unroll
    for (int r = 0; r < 4; ++r) T4[r] = __shfl(Tj, lk * 4 + r, 64);

    // ---- Pass B: register-only packed NEWTON iterations ----
    for (int it = 0; it < 6; ++it) {
        const int buf = (it + 1) & 1;
        f16x2 T2[4];
#pragma unroll
        for (int r = 0; r < 4; ++r) T2[r] = cvt_pk(T4[r], T4[r]);
        float f4[4] = {}, fp4[4] = {};
#pragma unroll
        for (int jp = 0; jp < 12; ++jp)
#pragma unroll
            for (int r = 0; r < 4; ++r) {
                f16x2 zc = __builtin_elementwise_max(zw[jp][r] - T2[r], zero2);
                f4[r]  = __builtin_amdgcn_fdot2(zc, zc, f4[r], false);
                fp4[r] = __builtin_amdgcn_fdot2(zc, one2, fp4[r], false);
            }
#pragma unroll
        for (int off = 1; off < 16; off <<= 1) {
#pragma unroll
            for (int r = 0; r < 4; ++r) {
                f4[r]  += __shfl_xor(f4[r],  off, 64);
                fp4[r] += __shfl_xor(fp4[r], off, 64);
            }
        }
        if (lr == 0) {
#pragma unroll
            for (int r = 0; r < 4; ++r) {
                sred[buf][w][lk * 4 + r][0] = f4[r];
                sred[buf][w][lk * 4 + r][1] = fp4[r];
            }
        }
        __syncthreads();
        float fj = 0.f, fpj = 0.f;
#pragma unroll
        for (int ww = 0; ww < 8; ++ww) {
            fj  += sred[buf][ww][lr][0];
            fpj += sred[buf][ww][lr][1];
        }
        float del = (fj - 1.0f) / (2.0f * fpj + 1e-20f);   // Newton step
        Tj += del;
#pragma unroll
        for (int r = 0; r < 4; ++r) T4[r] = __shfl(Tj, lk * 4 + r, 64);
        if (__all(fabsf(del) < 1e-6f)) break;   // block-uniform
    }

    // ---- Phase T: P -> plds -> transposed azw + attn stores ----
    f16x2 T2[4];
#pragma unroll
    for (int r = 0; r < 4; ++r) T2[r] = cvt_pk(T4[r], T4[r]);
    float* arow_t = attn + ((size_t)h * S + q0 + lr) * S + kbase + lk * 4;
    f16x8 azw[12];
#pragma unroll
    for (int jp = 0; jp < 12; ++jp) {
        const int buf = jp & 1;
        union { f16x2 h2[4]; f16x8 v; } pw;
#pragma unroll
        for (int r = 0; r < 4; ++r) {
            f16x2 zc = __builtin_elementwise_max(zw[jp][r] - T2[r], zero2);
            pw.h2[r] = zc * zc;
        }
        *(f16x8*)&plds[buf][w][lr][lk * 4] = pw.v;
        union { f16x2 h2[4]; f16x8 v; } au;
#pragma unroll
        for (int u = 0; u < 4; ++u) au.h2[u] = plds[buf][w][lk * 4 + u][lr];
        azw[jp] = au.v;
        f32x4 lo = {(float)au.v[0], (float)au.v[2], (float)au.v[4], (float)au.v[6]};
        f32x4 hi = {(float)au.v[1], (float)au.v[3], (float)au.v[5], (float)au.v[7]};
        __builtin_nontemporal_store(lo, (f32x4*)(arow_t + jp * 32));
        __builtin_nontemporal_store(hi, (f32x4*)(arow_t + jp * 32 + 16));
    }

    // ---- Phase PV: per dv-quarter, 4-reg acc, imm-offset V loads ----
#pragma unroll
    for (int j = 0; j < 4; ++j) {
        const _Float16* vpj = Vh + (size_t)(j * 16 + lr) * S + kbase + lk * 8;
        f32x4 a4 = (f32x4){0.f, 0.f, 0.f, 0.f};
#pragma unroll
        for (int jp = 0; jp < 12; ++jp) {
            f16x8 b = *(const f16x8*)(vpj + jp * 32);
            a4 = __builtin_amdgcn_mfma_f32_16x16x32_f16(azw[jp], b, a4, 0, 0, 0);
        }
#pragma unroll
        for (int r = 0; r < 4; ++r)
            atomicAdd(&pacc[lk * 4 + r][j * 16 + lr], a4[r]);
    }
    __syncthreads();
    _Float16* AOr = AOh + (size_t)q0 * 512 + h * 64;
#pragma unroll
    for (int u = 0; u < 2; ++u) {
        int idx = t + 512 * u;             // 0..1023
        int row = idx >> 6, col = idx & 63;
        AOr[(size_t)row * 512 + col] = (_Float16)pacc[row][col];
    }
}

// -------------------- K5: out-proj + residual + LayerNorm (MFMA, 8 waves) --------------------
__global__ __launch_bounds__(512) void outproj_mfma_kernel(
        const _Float16* __restrict__ AOh, const _Float16* __restrict__ WtAll,
        const float* __restrict__ bo, const float* __restrict__ x,
        const float* __restrict__ gamma, const float* __restrict__ beta,
        float* __restrict__ out) {
    __shared__ float red[8][16][2];
    const int s0 = blockIdx.x * 16;
    const int t = threadIdx.x, w = t >> 6, l = t & 63;
    const int lr = l & 15, lk = l >> 4;
    const _Float16* Ar = AOh + (size_t)(s0 + lr) * 512 + lk * 8;
    const _Float16* Br = WtAll + (size_t)(1536 + w * 64 + lr) * 512 + lk * 8;

    f32x4 acc[4];
#pragma unroll
    for (int j = 0; j < 4; ++j) acc[j] = (f32x4){0.f, 0.f, 0.f, 0.f};
    for (int ks = 0; ks < 16; ++ks) {
        f16x8 a = *(const f16x8*)(Ar + ks * 32);
#pragma unroll
        for (int j = 0; j < 4; ++j) {
            f16x8 b = *(const f16x8*)(Br + (size_t)(j * 16) * 512 + ks * 32);
            acc[j] = __builtin_amdgcn_mfma_f32_16x16x32_f16(a, b, acc[j], 0, 0, 0);
        }
    }
    float s_[4] = {}, q_[4] = {};
#pragma unroll
    for (int j = 0; j < 4; ++j) {
        const int col = w * 64 + j * 16 + lr;
        const float b0 = bo[col];
#pragma unroll
        for (int r = 0; r < 4; ++r) {
            float y = acc[j][r] + b0 + x[(size_t)(s0 + lk * 4 + r) * 512 + col];
            acc[j][r] = y;
            s_[r] += y;
            q_[r] = fmaf(y, y, q_[r]);
        }
    }
#pragma unroll
    for (int off = 1; off < 16; off <<= 1) {
#pragma unroll
        for (int r = 0; r < 4; ++r) {
            s_[r] += __shfl_xor(s_[r], off, 64);
            q_[r] += __shfl_xor(q_[r], off, 64);
        }
    }
    if (lr == 0) {
#pragma unroll
        for (int r = 0; r < 4; ++r) {
            red[w][lk * 4 + r][0] = s_[r];
            red[w][lk * 4 + r][1] = q_[r];
        }
    }
    __syncthreads();
#pragma unroll
    for (int r = 0; r < 4; ++r) {
        const int rowi = lk * 4 + r;
        float sj = 0.f, qj = 0.f;
#pragma unroll
        for (int ww = 0; ww < 8; ++ww) { sj += red[ww][rowi][0]; qj += red[ww][rowi][1]; }
        float mu  = sj * (1.0f / 512.0f);
        float var = qj * (1.0f / 512.0f) - mu * mu;
        float inv = rsqrtf(var + LN_EPS);
        const size_t rbase = (size_t)(s0 + rowi) * 512;
#pragma unroll
        for (int j = 0; j < 4; ++j) {
            const int col = w * 64 + j * 16 + lr;
            out[rbase + col] = (acc[j][r] - mu) * inv * gamma[col] + beta[col];
        }
    }
}

extern "C" void kernel_launch(void* const* d_in, const int* in_sizes, int n_in,
                              void* d_out, int out_size, void* d_ws, size_t ws_size,
                              hipStream_t stream) {
    const float* x     = (const float*)d_in[0];
    const float* Wq    = (const float*)d_in[1];
    const float* bq    = (const float*)d_in[2];
    const float* Wk    = (const float*)d_in[3];
    const float* bk    = (const float*)d_in[4];
    const float* Wv    = (const float*)d_in[5];
    const float* bv    = (const float*)d_in[6];
    const float* Wo    = (const float*)d_in[7];
    const float* bo    = (const float*)d_in[8];
    const float* gamma = (const float*)d_in[9];
    const float* beta  = (const float*)d_in[10];

    float* out  = (float*)d_out;
    float* attn = out + (size_t)S * D;          // tuple output #2

    _Float16* Qb    = (_Float16*)d_ws;          // [H][S][64] fp16, pre-scaled 1/16
    _Float16* Kb    = Qb + (size_t)H * S * 64;  // [H][S][64] fp16
    _Float16* Vt    = Kb + (size_t)H * S * 64;  // [H][64][S] fp16, k-interleaved
    _Float16* xh    = Vt + (size_t)H * S * 64;  // [S][512] fp16
    _Float16* WtAll = xh + (size_t)S * 512;     // [2048][512] fp16
    _Float16* AOh   = WtAll + (size_t)2048 * 512; // [S][512] fp16

    prep_w_kernel<<<dim3(2, 8, 4), 256, 0, stream>>>(Wq, Wk, Wv, Wo, WtAll);
    prep_x_kernel<<<dim3(S * D / 2048), 256, 0, stream>>>(x, xh);
    qkv_mfma_kernel<<<dim3(48, 24), 256, 0, stream>>>(xh, WtAll, bq, bk, bv, Qb, Kb, Vt);
    fused_attn_kernel<<<dim3((S / 16) * H), 512, 0, stream>>>(Qb, Kb, Vt, attn, AOh);
    outproj_mfma_kernel<<<dim3(S / 16), 512, 0, stream>>>(AOh, WtAll, bo, x, gamma, beta, out);
}